// Round 10
// baseline (146.940 us; speedup 1.0000x reference)
//
#include <hip/hip_runtime.h>

#define T_   16
#define B_   8
#define N_   8
#define H_   128
#define C_   32
#define HW_  256
#define TAR_ 145
#define G4H  512
#define MEMIN 8593
#define AK   8512   // padded K (multiple of 64)
#define XGN  524288 // elements per xg buffer
#define KSTEP 64
#define PANEL_E 136192   // 16 rows * 8512 k, elements per bf16 B panel

typedef __attribute__((ext_vector_type(8))) short short8v;
typedef __attribute__((ext_vector_type(4))) float f32x4;
typedef __attribute__((ext_vector_type(4), aligned(4))) float f32x4u;

__device__ __forceinline__ float bf2f(unsigned short u){
  return __uint_as_float(((unsigned int)u) << 16);
}
__device__ __forceinline__ unsigned short f2bf(float x){
  unsigned int b = __float_as_uint(x);
  return (unsigned short)((b + 0x7fffu + ((b >> 16) & 1u)) >> 16);
}
// pack two f32 -> two bf16 (RN ties-away) in one dword: low16=bf16(lo)
__device__ __forceinline__ unsigned pkbf(float lo, float hi){
  return __builtin_amdgcn_perm(__float_as_uint(hi) + 0x8000u,
                               __float_as_uint(lo) + 0x8000u, 0x07060302u);
}
__device__ __forceinline__ float bflo(unsigned w){ return __uint_as_float(w << 16); }
__device__ __forceinline__ float bfhi(unsigned w){ return __uint_as_float(w & 0xffff0000u); }
__device__ __forceinline__ float sigf(float x){ return 1.f/(1.f + expf(-x)); }

__device__ __forceinline__ void gl_lds16(const void* g, void* l){
  __builtin_amdgcn_global_load_lds(
      (const __attribute__((address_space(1))) unsigned int*)g,
      (__attribute__((address_space(3))) unsigned int*)l, 16, 0, 0);
}
__device__ __forceinline__ void gl_lds4(const void* g, void* l){
  __builtin_amdgcn_global_load_lds(
      (const __attribute__((address_space(1))) unsigned int*)g,
      (__attribute__((address_space(3))) unsigned int*)l, 4, 0, 0);
}

// ---------------------------------------------------------------------------
// shared[h] = Wo_b[h] + sum_d Wv_b[d] * Wo_w[h,d]   (attention collapses)
// ---------------------------------------------------------------------------
__global__ void k_shared(const float* __restrict__ WvB, const float* __restrict__ WoW,
                         const float* __restrict__ WoB, float* __restrict__ sh){
  const int h = blockIdx.x, lane = threadIdx.x;
  float acc = 0.f;
  for(int d = lane; d < 896; d += 64) acc += WvB[d] * WoW[h*896 + d];
  for(int s = 32; s; s >>= 1) acc += __shfl_down(acc, s);
  if(lane == 0) sh[h] = acc + WoB[h];
}

// ---------------------------------------------------------------------------
// gate[tb,n,c] = sigmoid(td_b[n,c] + sum_{x<145} tar[tb,x]*td_w[n,c,x])
// ---------------------------------------------------------------------------
__global__ __launch_bounds__(256) void k_gate(const float* __restrict__ tar,
                                              const float* __restrict__ tdw,
                                              const float* __restrict__ tdb,
                                              float* __restrict__ gate){
  __shared__ float twS[32*145];
  __shared__ float taS[16*145];
  const int tb0 = blockIdx.x * 16, n = blockIdx.y, tid = threadIdx.x;
  for(int i = tid; i < 32*145; i += 256){
    int c = i / 145, x = i - c*145;
    twS[i] = tdw[(n*32 + c)*273 + x];
  }
  for(int i = tid; i < 16*145; i += 256)
    taS[i] = tar[tb0*145 + i];
  __syncthreads();
  for(int o = tid; o < 512; o += 256){
    int r = o >> 5, c = o & 31;
    float a = tdb[n*32 + c];
    const float* tr = &taS[r*145];
    const float* tw = &twS[c*145];
    for(int x = 0; x < 145; ++x) a += tr[x]*tw[x];
    gate[((tb0 + r)*N_ + n)*C_ + c] = 1.f/(1.f + expf(-a));
  }
}

// ---------------------------------------------------------------------------
// conv v2: grid (tb=128, n=8), 256 threads = hw.  Tail covers [8192..8512).
// ---------------------------------------------------------------------------
__global__ __launch_bounds__(256) void k_conv2(
    const float* __restrict__ img, const float* __restrict__ gate,
    const float* __restrict__ cw, const float* __restrict__ cb,
    const float* __restrict__ sh, const float* __restrict__ tar,
    unsigned short* __restrict__ mem)
{
  __shared__ float imgS[8192];    // [c][hw]
  __shared__ float cwgT[1024];    // [c][d] = cw[d][c]*gate[n][c]
  const int tb = blockIdx.x, n = blockIdx.y;
  const int hw = threadIdx.x;
  for(int i = hw; i < 8192; i += 256)
    imgS[i] = img[(size_t)tb*8192 + i];
  for(int i = hw; i < 1024; i += 256){
    const int c = i >> 5, d = i & 31;
    cwgT[i] = cw[d*32 + c] * gate[(tb*8 + n)*32 + c];
  }
  __syncthreads();
  f32x4 acc[8];
  #pragma unroll
  for(int dq = 0; dq < 8; ++dq){
    const f32x4u cv = *(const f32x4u*)&cb[dq*4];
    acc[dq].x = cv.x; acc[dq].y = cv.y; acc[dq].z = cv.z; acc[dq].w = cv.w;
  }
  #pragma unroll 4
  for(int c = 0; c < 32; ++c){
    const float iv = imgS[c*256 + hw];
    #pragma unroll
    for(int dq = 0; dq < 8; ++dq){
      const f32x4 w = *(const f32x4*)&cwgT[c*32 + dq*4];
      acc[dq].x += iv*w.x; acc[dq].y += iv*w.y;
      acc[dq].z += iv*w.z; acc[dq].w += iv*w.w;
    }
  }
  unsigned short* mrow = mem + (size_t)(n*128 + tb)*AK;
  #pragma unroll
  for(int dq = 0; dq < 8; ++dq){
    mrow[(dq*4 + 0)*256 + hw] = f2bf(acc[dq].x);
    mrow[(dq*4 + 1)*256 + hw] = f2bf(acc[dq].y);
    mrow[(dq*4 + 2)*256 + hw] = f2bf(acc[dq].z);
    mrow[(dq*4 + 3)*256 + hw] = f2bf(acc[dq].w);
  }
  for(int i = hw; i < 320; i += 256){
    if(i < 128)      mrow[8192 + i]       = f2bf(sh[i]);
    else if(i < 273) mrow[8320 + i - 128] = f2bf(tar[tb*TAR_ + i - 128]);
    else             mrow[8465 + i - 273] = 0;   // zeros to 8512
  }
}

// ---------------------------------------------------------------------------
// wprep: linear-read Wih (copy-like, full-BW pattern), convert f32->bf16,
// write contiguous per-block panels in LDS-stage order:
//   panel(n,gt)[kb][g][ksw]  (kb = k/64 chunk of 16x64 bf16 = 2KB,
//   ksw = ((kin>>3)^(g&7))<<3 | kin&7  — round-9 XOR swizzle baked in)
// Reads: consecutive threads -> consecutive 32B (HBM page friendly).
// ---------------------------------------------------------------------------
__global__ __launch_bounds__(256) void k_wprep(
    const float* __restrict__ Wih, unsigned short* __restrict__ wsB)
{
  const unsigned J = 4358144u;      // 4096 rows * 1064 oct-chunks
  const unsigned stride = gridDim.x * 256u;
  for(unsigned j = blockIdx.x*256u + threadIdx.x; j < J; j += stride){
    const unsigned r  = j / 1064u;            // src row = n*512 + g512
    const unsigned k0 = (j - r*1064u) * 8u;   // 0..8504, mult of 8
    const float* src = Wih + (size_t)r*MEMIN + k0;
    const f32x4u v0 = *(const f32x4u*)src;
    const f32x4u v1 = *(const f32x4u*)(src + 4);
    uint4 o;
    o.x = pkbf(v0.x, v0.y); o.y = pkbf(v0.z, v0.w);
    o.z = pkbf(v1.x, v1.y); o.w = pkbf(v1.z, v1.w);
    const unsigned n = r >> 9, g512 = r & 511u;
    const unsigned gt = g512 >> 4, g = g512 & 15u;
    const unsigned kb = k0 >> 6, kin = k0 & 63u;
    const unsigned ksw = (((kin >> 3) ^ (g & 7u)) << 3);
    unsigned short* dst = wsB + (size_t)(n*32u + gt)*PANEL_E
                          + kb*1024u + g*64u + ksw;
    *(uint4*)dst = o;
  }
}

// ---------------------------------------------------------------------------
// MFMA GEMM v6: round-8 structure; B streams CONTIGUOUSLY from bf16 panel
// (one sequential 68KB stream per block, 2KB/stage) -> DRAM-page friendly;
// no f32->bf16 pack in the loop.  A path identical to round 9 (passing).
// C/D: col=lane&15, row=(lane>>4)*4+j.
// ---------------------------------------------------------------------------
__global__ __launch_bounds__(256) void k_gemm6(
    const unsigned short* __restrict__ mem, const unsigned short* __restrict__ wsB,
    float* __restrict__ xg4)
{
  __shared__ unsigned short Abuf[2][128*64];   // 16 KB each, linear
  __shared__ unsigned short Bbuf[2][16*64];    //  2 KB each: [g][64k bf16]
  const int gt = blockIdx.x, n = blockIdx.y, ks = blockIdx.z;
  const int tid = threadIdx.x;
  const int wv = tid >> 6, ln = tid & 63;
  const int lr = ln & 15, lg = ln >> 4;
  const int g0 = gt*16;
  const int kbeg = (ks == 0) ? 0 : 2176 + (ks - 1)*2112;
  const int nsteps = (ks == 0) ? 34 : 33;     // 34+33*3 = 133 steps * 64 = 8512
  const unsigned short* An = mem + (size_t)n*128*AK;
  const char* panelB = (const char*)(wsB + (size_t)(n*32 + gt)*PANEL_E);

#define STAGE6(bb, kk) do{                                                     \
    _Pragma("unroll")                                                          \
    for(int i_ = 0; i_ < 4; ++i_){                                             \
      const int ci_ = i_*256 + tid;                                            \
      const int row_ = ci_ >> 3;                                               \
      const unsigned short* src_ = An + (size_t)row_*AK + (kk)                 \
                                   + (((ci_ & 7) ^ (row_ & 7)) << 3);          \
      gl_lds16(src_, &Abuf[bb][(i_*256 + wv*64)*8]);                           \
    }                                                                          \
    _Pragma("unroll")                                                          \
    for(int j_ = 0; j_ < 2; ++j_){                                             \
      const char* srcB_ = panelB + (size_t)((kk) >> 6)*2048                    \
                          + wv*512 + j_*256 + ln*4;                            \
      gl_lds4(srcB_, (char*)&Bbuf[bb][0] + wv*512 + j_*256);                   \
    }                                                                          \
  }while(0)

  f32x4 acc0 = {0.f,0.f,0.f,0.f};
  f32x4 acc1 = {0.f,0.f,0.f,0.f};

  STAGE6(0, kbeg);
  __syncthreads();

  int b = 0;
  for(int t = 0; t < nsteps; ++t){
    if(t + 1 < nsteps) STAGE6(b^1, kbeg + (t+1)*KSTEP);
    #pragma unroll
    for(int s = 0; s < 2; ++s){
      const int jb = (s*4 + lg) ^ (lr & 7);
      const short8v bf = *(const short8v*)&Bbuf[b][lr*64 + jb*8];
      const short8v a0 = *(const short8v*)&Abuf[b][(wv*32 + lr)*64 + jb*8];
      const short8v a1 = *(const short8v*)&Abuf[b][(wv*32 + 16 + lr)*64 + jb*8];
      acc0 = __builtin_amdgcn_mfma_f32_16x16x32_bf16(a0, bf, acc0, 0, 0, 0);
      acc1 = __builtin_amdgcn_mfma_f32_16x16x32_bf16(a1, bf, acc1, 0, 0, 0);
    }
    __syncthreads();
    b ^= 1;
  }
#undef STAGE6

  float* dst = xg4 + (size_t)ks*XGN;
  const int c0 = g0 + lr;
  const int r0 = wv*32 + lg*4, r1 = r0 + 16;
  #pragma unroll
  for(int j = 0; j < 4; ++j){
    dst[(size_t)((r0 + j)*8 + n)*G4H + c0] = acc0[j];
    dst[(size_t)((r1 + j)*8 + n)*G4H + c0] = acc1[j];
  }
}

// ---------------------------------------------------------------------------
// Fallback GEMM (round-9 verified): direct f32 Wih via DMA + counted vmcnt.
// Used only if ws_size < WS_AP.
// ---------------------------------------------------------------------------
__global__ __launch_bounds__(256) void k_gemm5(
    const unsigned short* __restrict__ mem, const float* __restrict__ Wih,
    float* __restrict__ xg4)
{
  __shared__ unsigned short Abuf[2][128*64];
  __shared__ float          Bbuf[2][16*64];
  const int gt = blockIdx.x, n = blockIdx.y, ks = blockIdx.z;
  const int tid = threadIdx.x;
  const int wv = tid >> 6, ln = tid & 63;
  const int lr = ln & 15, lg = ln >> 4;
  const int g0 = gt*16;
  const int kbeg = (ks == 0) ? 0 : 2176 + (ks - 1)*2112;
  const int nsteps = (ks == 0) ? 34 : 33;
  const unsigned short* An = mem + (size_t)n*128*AK;
  const float* Bn = Wih + (size_t)(n*G4H + g0)*MEMIN;

#define STAGE5(bb, kk) do{                                                     \
    _Pragma("unroll")                                                          \
    for(int i_ = 0; i_ < 4; ++i_){                                             \
      const int ci_ = i_*256 + tid;                                            \
      const int row_ = ci_ >> 3;                                               \
      const unsigned short* src_ = An + (size_t)row_*AK + (kk)                 \
                                   + (((ci_ & 7) ^ (row_ & 7)) << 3);          \
      gl_lds16(src_, &Abuf[bb][(i_*256 + wv*64)*8]);                           \
    }                                                                          \
    _Pragma("unroll")                                                          \
    for(int q_ = 0; q_ < 4; ++q_){                                             \
      const int idx_ = q_*256 + tid;                                           \
      const int g_ = idx_ >> 6;                                                \
      const int kd_ = idx_ & 63;                                               \
      const float* srcB_ = Bn + (size_t)g_*MEMIN + (kk)                        \
                           + ((((kd_ >> 3) ^ (g_ & 7)) << 3) + (kd_ & 7));     \
      gl_lds4(srcB_, &Bbuf[bb][q_*256 + wv*64]);                               \
    }                                                                          \
  }while(0)

  f32x4 acc0 = {0.f,0.f,0.f,0.f};
  f32x4 acc1 = {0.f,0.f,0.f,0.f};

  STAGE5(0, kbeg);
  if(nsteps > 1) STAGE5(1, kbeg + KSTEP);

  int b = 0;
  for(int t = 0; t < nsteps; ++t){
    if(t < nsteps - 1){
      asm volatile("s_waitcnt vmcnt(8)" ::: "memory");
    } else {
      asm volatile("s_waitcnt vmcnt(0)" ::: "memory");
    }
    __builtin_amdgcn_s_barrier();
    #pragma unroll
    for(int s = 0; s < 2; ++s){
      const int jb = (s*4 + lg) ^ (lr & 7);
      const float* bp = &Bbuf[b][lr*64 + jb*8];
      const f32x4 blo = *(const f32x4*)bp;
      const f32x4 bhi = *(const f32x4*)(bp + 4);
      short8v bf;
      unsigned* u = (unsigned*)&bf;
      u[0] = pkbf(blo.x, blo.y); u[1] = pkbf(blo.z, blo.w);
      u[2] = pkbf(bhi.x, bhi.y); u[3] = pkbf(bhi.z, bhi.w);
      const short8v a0 = *(const short8v*)&Abuf[b][(wv*32 + lr)*64 + jb*8];
      const short8v a1 = *(const short8v*)&Abuf[b][(wv*32 + 16 + lr)*64 + jb*8];
      acc0 = __builtin_amdgcn_mfma_f32_16x16x32_bf16(a0, bf, acc0, 0, 0, 0);
      acc1 = __builtin_amdgcn_mfma_f32_16x16x32_bf16(a1, bf, acc1, 0, 0, 0);
    }
    __builtin_amdgcn_s_barrier();
    if(t + 2 < nsteps) STAGE5(b, kbeg + (t+2)*KSTEP);
    b ^= 1;
  }
#undef STAGE5

  float* dst = xg4 + (size_t)ks*XGN;
  const int c0 = g0 + lr;
  const int r0 = wv*32 + lg*4, r1 = r0 + 16;
  #pragma unroll
  for(int j = 0; j < 4; ++j){
    dst[(size_t)((r0 + j)*8 + n)*G4H + c0] = acc0[j];
    dst[(size_t)((r1 + j)*8 + n)*G4H + c0] = acc1[j];
  }
}

// ---------------------------------------------------------------------------
// LSTM v2: 64 blocks = (b,n) pairs, 512 threads = gate-row g.
// ---------------------------------------------------------------------------
__global__ __launch_bounds__(512) void k_lstm2(
    const float* __restrict__ xg4, const float* __restrict__ Whh,
    const float* __restrict__ bih, const float* __restrict__ bhh,
    float* __restrict__ out)
{
  __shared__ float hS[128];
  __shared__ float preS[512];
  const int bn = blockIdx.x;
  const int n = bn & 7, b = bn >> 3;
  const int g = threadIdx.x;

  unsigned wr[64];
  const float* wrow = Whh + (size_t)(n*G4H + g)*H_;
  #pragma unroll
  for(int i = 0; i < 32; ++i){
    const f32x4 w = *(const f32x4*)(wrow + i*4);
    wr[2*i]   = pkbf(w.x, w.y);
    wr[2*i+1] = pkbf(w.z, w.w);
  }
  const float bias = bih[n*G4H + g] + bhh[n*G4H + g];
  if(g < 128) hS[g] = 0.f;
  float cc = 0.f;
  __syncthreads();

  for(int t = 0; t < 16; ++t){
    const size_t xb = (size_t)((t*8 + b)*8 + n)*G4H + g;
    float acc = bias + xg4[xb] + xg4[xb + XGN] + xg4[xb + 2*XGN] + xg4[xb + 3*XGN];
    #pragma unroll
    for(int q = 0; q < 32; ++q){
      const f32x4 hv = *(const f32x4*)&hS[q*4];
      const unsigned w0 = wr[2*q], w1 = wr[2*q+1];
      acc += hv.x*bflo(w0) + hv.y*bfhi(w0) + hv.z*bflo(w1) + hv.w*bfhi(w1);
    }
    preS[g] = acc;
    __syncthreads();
    if(g < 128){
      const float iv = sigf(preS[g]);
      const float fv = sigf(preS[128 + g]);
      const float gv = tanhf(preS[256 + g]);
      const float ov = sigf(preS[384 + g]);
      cc = fv*cc + iv*gv;
      const float hn = ov*tanhf(cc);
      hS[g] = hn;
      out[(t*8 + b)*1024 + n*128 + g] = hn;
      if(t == 15){
        out[131072 + (b*8 + n)*128 + g] = hn;   // hT
        out[139264 + (b*8 + n)*128 + g] = cc;   // cT
      }
    }
    __syncthreads();
  }
}

// ---------------------------------------------------------------------------
extern "C" void kernel_launch(void* const* d_in, const int* in_sizes, int n_in,
                              void* d_out, int out_size, void* d_ws, size_t ws_size,
                              hipStream_t stream)
{
  (void)in_sizes; (void)n_in; (void)out_size;
  const float* img  = (const float*)d_in[0];
  const float* tar  = (const float*)d_in[1];
  const float* WvB  = (const float*)d_in[7];
  const float* WoW  = (const float*)d_in[8];
  const float* WoB  = (const float*)d_in[9];
  const float* tdw  = (const float*)d_in[10];
  const float* tdb  = (const float*)d_in[11];
  const float* cw   = (const float*)d_in[12];
  const float* cb   = (const float*)d_in[13];
  const float* Wih  = (const float*)d_in[14];
  const float* Whh  = (const float*)d_in[15];
  const float* bih  = (const float*)d_in[16];
  const float* bhh  = (const float*)d_in[17];

  float* wsf   = (float*)d_ws;
  float* gatew = wsf;                       // 32768 f
  float* shw   = wsf + 32768;               // 128 f
  float* xg4w  = wsf + 32896;               // 4 x 524288 f, ends @ 8,520,192 B
  unsigned short* memA = (unsigned short*)((char*)d_ws + 8520192);   // 17.4 MB
  unsigned short* wsB  = (unsigned short*)((char*)d_ws + 25952768);  // 69.7 MB
  const size_t WS_A  = 25952768;                               // round-9 tier
  const size_t WS_AP = 25952768 + (size_t)256*PANEL_E*2;       // 95,683,072 B

  k_shared<<<128, 64, 0, stream>>>(WvB, WoW, WoB, shw);
  k_gate<<<dim3(8, 8), 256, 0, stream>>>(tar, tdw, tdb, gatew);
  k_conv2<<<dim3(128, 8), 256, 0, stream>>>(img, gatew, cw, cb, shw, tar, memA);

  if(ws_size >= WS_AP){
    k_wprep<<<2048, 256, 0, stream>>>(Wih, wsB);
    k_gemm6<<<dim3(32, 8, 4), 256, 0, stream>>>(memA, wsB, xg4w);
  } else if(ws_size >= WS_A){
    k_gemm5<<<dim3(32, 8, 4), 256, 0, stream>>>(memA, Wih, xg4w);
  }
  k_lstm2<<<64, 512, 0, stream>>>(xg4w, Whh, bih, bhh, (float*)d_out);
}

// Round 11
// 125.109 us; speedup vs baseline: 1.1745x; 1.1745x over previous
//
#include <hip/hip_runtime.h>

#define T_   16
#define B_   8
#define N_   8
#define H_   128
#define C_   32
#define HW_  256
#define TAR_ 145
#define G4H  512
#define MEMIN 8593
#define AK   8512   // padded K (multiple of 64)
#define XGN  524288
#define KSTEP 64

typedef __attribute__((ext_vector_type(8))) short short8v;
typedef __attribute__((ext_vector_type(4))) float f32x4;
typedef __attribute__((ext_vector_type(4), aligned(4))) float f32x4u;

__device__ __forceinline__ float bf2f(unsigned short u){
  return __uint_as_float(((unsigned int)u) << 16);
}
__device__ __forceinline__ unsigned short f2bf(float x){
  unsigned int b = __float_as_uint(x);
  return (unsigned short)((b + 0x7fffu + ((b >> 16) & 1u)) >> 16);
}
__device__ __forceinline__ unsigned pkbf(float lo, float hi){
  return __builtin_amdgcn_perm(__float_as_uint(hi) + 0x8000u,
                               __float_as_uint(lo) + 0x8000u, 0x07060302u);
}
__device__ __forceinline__ float bflo(unsigned w){ return __uint_as_float(w << 16); }
__device__ __forceinline__ float bfhi(unsigned w){ return __uint_as_float(w & 0xffff0000u); }
__device__ __forceinline__ float sigf(float x){ return 1.f/(1.f + expf(-x)); }

__device__ __forceinline__ void gl_lds16(const void* g, void* l){
  __builtin_amdgcn_global_load_lds(
      (const __attribute__((address_space(1))) unsigned int*)g,
      (__attribute__((address_space(3))) unsigned int*)l, 16, 0, 0);
}
__device__ __forceinline__ void gl_lds4(const void* g, void* l){
  __builtin_amdgcn_global_load_lds(
      (const __attribute__((address_space(1))) unsigned int*)g,
      (__attribute__((address_space(3))) unsigned int*)l, 4, 0, 0);
}

// ---------------------------------------------------------------------------
// shared[h] = Wo_b[h] + sum_d Wv_b[d] * Wo_w[h,d]   (attention collapses)
// ---------------------------------------------------------------------------
__global__ void k_shared(const float* __restrict__ WvB, const float* __restrict__ WoW,
                         const float* __restrict__ WoB, float* __restrict__ sh){
  const int h = blockIdx.x, lane = threadIdx.x;
  float acc = 0.f;
  for(int d = lane; d < 896; d += 64) acc += WvB[d] * WoW[h*896 + d];
  for(int s = 32; s; s >>= 1) acc += __shfl_down(acc, s);
  if(lane == 0) sh[h] = acc + WoB[h];
}

// ---------------------------------------------------------------------------
// gate[tb,n,c] = sigmoid(td_b[n,c] + sum_{x<145} tar[tb,x]*td_w[n,c,x])
// ---------------------------------------------------------------------------
__global__ __launch_bounds__(256) void k_gate(const float* __restrict__ tar,
                                              const float* __restrict__ tdw,
                                              const float* __restrict__ tdb,
                                              float* __restrict__ gate){
  __shared__ float twS[32*145];
  __shared__ float taS[16*145];
  const int tb0 = blockIdx.x * 16, n = blockIdx.y, tid = threadIdx.x;
  for(int i = tid; i < 32*145; i += 256){
    int c = i / 145, x = i - c*145;
    twS[i] = tdw[(n*32 + c)*273 + x];
  }
  for(int i = tid; i < 16*145; i += 256)
    taS[i] = tar[tb0*145 + i];
  __syncthreads();
  for(int o = tid; o < 512; o += 256){
    int r = o >> 5, c = o & 31;
    float a = tdb[n*32 + c];
    const float* tr = &taS[r*145];
    const float* tw = &twS[c*145];
    for(int x = 0; x < 145; ++x) a += tr[x]*tw[x];
    gate[((tb0 + r)*N_ + n)*C_ + c] = 1.f/(1.f + expf(-a));
  }
}

// ---------------------------------------------------------------------------
// conv v2: grid (tb=128, n=8), 256 threads = hw.  Tail covers [8192..8512).
// ---------------------------------------------------------------------------
__global__ __launch_bounds__(256) void k_conv2(
    const float* __restrict__ img, const float* __restrict__ gate,
    const float* __restrict__ cw, const float* __restrict__ cb,
    const float* __restrict__ sh, const float* __restrict__ tar,
    unsigned short* __restrict__ mem)
{
  __shared__ float imgS[8192];    // [c][hw]
  __shared__ float cwgT[1024];    // [c][d] = cw[d][c]*gate[n][c]
  const int tb = blockIdx.x, n = blockIdx.y;
  const int hw = threadIdx.x;
  for(int i = hw; i < 8192; i += 256)
    imgS[i] = img[(size_t)tb*8192 + i];
  for(int i = hw; i < 1024; i += 256){
    const int c = i >> 5, d = i & 31;
    cwgT[i] = cw[d*32 + c] * gate[(tb*8 + n)*32 + c];
  }
  __syncthreads();
  f32x4 acc[8];
  #pragma unroll
  for(int dq = 0; dq < 8; ++dq){
    const f32x4u cv = *(const f32x4u*)&cb[dq*4];
    acc[dq].x = cv.x; acc[dq].y = cv.y; acc[dq].z = cv.z; acc[dq].w = cv.w;
  }
  #pragma unroll 4
  for(int c = 0; c < 32; ++c){
    const float iv = imgS[c*256 + hw];
    #pragma unroll
    for(int dq = 0; dq < 8; ++dq){
      const f32x4 w = *(const f32x4*)&cwgT[c*32 + dq*4];
      acc[dq].x += iv*w.x; acc[dq].y += iv*w.y;
      acc[dq].z += iv*w.z; acc[dq].w += iv*w.w;
    }
  }
  unsigned short* mrow = mem + (size_t)(n*128 + tb)*AK;
  #pragma unroll
  for(int dq = 0; dq < 8; ++dq){
    mrow[(dq*4 + 0)*256 + hw] = f2bf(acc[dq].x);
    mrow[(dq*4 + 1)*256 + hw] = f2bf(acc[dq].y);
    mrow[(dq*4 + 2)*256 + hw] = f2bf(acc[dq].z);
    mrow[(dq*4 + 3)*256 + hw] = f2bf(acc[dq].w);
  }
  for(int i = hw; i < 320; i += 256){
    if(i < 128)      mrow[8192 + i]       = f2bf(sh[i]);
    else if(i < 273) mrow[8320 + i - 128] = f2bf(tar[tb*TAR_ + i - 128]);
    else             mrow[8465 + i - 273] = 0;   // zeros to 8512
  }
}

// ---------------------------------------------------------------------------
// MFMA GEMM v7: NO K-split.  Grid = 256 blocks (n = bid&7 -> XCD-pinned so
// each schema's A (2.18MB) lives in one XCD L2).  Each block streams its 16
// B-rows SEQUENTIALLY over full K (4096 total streams ~16/HBM-channel ->
// open-page streaming; rounds 4-9's 16K streams thrashed pages at 1.7TB/s).
// Ring-4 LDS (80KB dynamic), 3-deep prefetch, counted vmcnt(16), one barrier
// per step.  Compute core/swizzle/layout identical to passing round 9.
// C/D: col=lane&15, row=(lane>>4)*4+j.
// ---------------------------------------------------------------------------
__global__ __launch_bounds__(256) void k_gemm7(
    const unsigned short* __restrict__ mem, const float* __restrict__ Wih,
    float* __restrict__ xg)
{
  extern __shared__ char smem7[];
  unsigned short (*Abuf)[128*64] = (unsigned short(*)[128*64])smem7;     // 4x16KB
  float (*Bbuf)[16*64] = (float(*)[16*64])(smem7 + 4*128*64*2);          // 4x4KB
  const int bid = blockIdx.x;
  const int n = bid & 7, gt = bid >> 3;
  const int tid = threadIdx.x;
  const int wv = tid >> 6, ln = tid & 63;
  const int lr = ln & 15, lg = ln >> 4;
  const int g0 = gt*16;
  const unsigned short* An = mem + (size_t)n*128*AK;
  const float* Bn = Wih + (size_t)(n*G4H + g0)*MEMIN;

#define STAGE7(sl, kk) do{                                                     \
    _Pragma("unroll")                                                          \
    for(int i_ = 0; i_ < 4; ++i_){                                             \
      const int ci_ = i_*256 + tid;                                            \
      const int row_ = ci_ >> 3;                                               \
      const unsigned short* src_ = An + (size_t)row_*AK + (kk)                 \
                                   + (((ci_ & 7) ^ (row_ & 7)) << 3);          \
      gl_lds16(src_, &Abuf[sl][(i_*256 + wv*64)*8]);                           \
    }                                                                          \
    _Pragma("unroll")                                                          \
    for(int q_ = 0; q_ < 4; ++q_){                                             \
      const int idx_ = q_*256 + tid;                                           \
      const int g_ = idx_ >> 6;                                                \
      const int kd_ = idx_ & 63;                                               \
      const float* srcB_ = Bn + (size_t)g_*MEMIN + (kk)                        \
                           + ((((kd_ >> 3) ^ (g_ & 7)) << 3) + (kd_ & 7));     \
      gl_lds4(srcB_, &Bbuf[sl][q_*256 + wv*64]);                               \
    }                                                                          \
  }while(0)

  f32x4 acc0 = {0.f,0.f,0.f,0.f};
  f32x4 acc1 = {0.f,0.f,0.f,0.f};

  STAGE7(0, 0);            // 8 vmem/wave
  STAGE7(1, KSTEP);        // 16 outstanding
  STAGE7(2, 2*KSTEP);      // 24 outstanding

  for(int t = 0; t < 133; ++t){
    if(t < 131){
      asm volatile("s_waitcnt vmcnt(16)" ::: "memory");  // stage t done; t+1,t+2 in flight
    } else if(t == 131){
      asm volatile("s_waitcnt vmcnt(8)" ::: "memory");
    } else {
      asm volatile("s_waitcnt vmcnt(0)" ::: "memory");
    }
    __builtin_amdgcn_s_barrier();
    const int sl = t & 3;
    #pragma unroll
    for(int s = 0; s < 2; ++s){
      const int jb = (s*4 + lg) ^ (lr & 7);
      const float* bp = &Bbuf[sl][lr*64 + jb*8];
      const f32x4 blo = *(const f32x4*)bp;
      const f32x4 bhi = *(const f32x4*)(bp + 4);
      short8v bf;
      unsigned* u = (unsigned*)&bf;
      u[0] = pkbf(blo.x, blo.y); u[1] = pkbf(blo.z, blo.w);
      u[2] = pkbf(bhi.x, bhi.y); u[3] = pkbf(bhi.z, bhi.w);
      const short8v a0 = *(const short8v*)&Abuf[sl][(wv*32 + lr)*64 + jb*8];
      const short8v a1 = *(const short8v*)&Abuf[sl][(wv*32 + 16 + lr)*64 + jb*8];
      acc0 = __builtin_amdgcn_mfma_f32_16x16x32_bf16(a0, bf, acc0, 0, 0, 0);
      acc1 = __builtin_amdgcn_mfma_f32_16x16x32_bf16(a1, bf, acc1, 0, 0, 0);
    }
    if(t + 3 < 133) STAGE7((t + 3) & 3, (t + 3)*KSTEP);
    // slot (t+3)&3 == (t-1)&3: its readers ran in step t-1, and this step's
    // barrier already guaranteed every wave finished step t-1.
  }
#undef STAGE7

  const int c0 = g0 + lr;
  const int r0 = wv*32 + lg*4, r1 = r0 + 16;
  #pragma unroll
  for(int j = 0; j < 4; ++j){
    xg[(size_t)((r0 + j)*8 + n)*G4H + c0] = acc0[j];
    xg[(size_t)((r1 + j)*8 + n)*G4H + c0] = acc1[j];
  }
}

// ---------------------------------------------------------------------------
// LSTM v2: 64 blocks = (b,n) pairs, 512 threads = gate-row g.  nsum = number
// of K-split partial buffers to sum (1 for gemm7).
// ---------------------------------------------------------------------------
__global__ __launch_bounds__(512) void k_lstm2(
    const float* __restrict__ xg4, int nsum, const float* __restrict__ Whh,
    const float* __restrict__ bih, const float* __restrict__ bhh,
    float* __restrict__ out)
{
  __shared__ float hS[128];
  __shared__ float preS[512];
  const int bn = blockIdx.x;
  const int n = bn & 7, b = bn >> 3;
  const int g = threadIdx.x;

  unsigned wr[64];
  const float* wrow = Whh + (size_t)(n*G4H + g)*H_;
  #pragma unroll
  for(int i = 0; i < 32; ++i){
    const f32x4 w = *(const f32x4*)(wrow + i*4);
    wr[2*i]   = pkbf(w.x, w.y);
    wr[2*i+1] = pkbf(w.z, w.w);
  }
  const float bias = bih[n*G4H + g] + bhh[n*G4H + g];
  if(g < 128) hS[g] = 0.f;
  float cc = 0.f;
  __syncthreads();

  for(int t = 0; t < 16; ++t){
    const size_t xb = (size_t)((t*8 + b)*8 + n)*G4H + g;
    float acc = bias;
    for(int u = 0; u < nsum; ++u) acc += xg4[xb + (size_t)u*XGN];
    #pragma unroll
    for(int q = 0; q < 32; ++q){
      const f32x4 hv = *(const f32x4*)&hS[q*4];
      const unsigned w0 = wr[2*q], w1 = wr[2*q+1];
      acc += hv.x*bflo(w0) + hv.y*bfhi(w0) + hv.z*bflo(w1) + hv.w*bfhi(w1);
    }
    preS[g] = acc;
    __syncthreads();
    if(g < 128){
      const float iv = sigf(preS[g]);
      const float fv = sigf(preS[128 + g]);
      const float gv = tanhf(preS[256 + g]);
      const float ov = sigf(preS[384 + g]);
      cc = fv*cc + iv*gv;
      const float hn = ov*tanhf(cc);
      hS[g] = hn;
      out[(t*8 + b)*1024 + n*128 + g] = hn;
      if(t == 15){
        out[131072 + (b*8 + n)*128 + g] = hn;   // hT
        out[139264 + (b*8 + n)*128 + g] = cc;   // cT
      }
    }
    __syncthreads();
  }
}

// ---------------------------------------------------------------------------
// Fallback GEMM (round-9 verified, k-split x4): only used if ws allows its
// larger xg4 layout but gemm7's is somehow unavailable — kept for safety.
// ---------------------------------------------------------------------------
__global__ __launch_bounds__(256) void k_gemm5(
    const unsigned short* __restrict__ mem, const float* __restrict__ Wih,
    float* __restrict__ xg4)
{
  __shared__ unsigned short Abuf[2][128*64];
  __shared__ float          Bbuf[2][16*64];
  const int gt = blockIdx.x, n = blockIdx.y, ks = blockIdx.z;
  const int tid = threadIdx.x;
  const int wv = tid >> 6, ln = tid & 63;
  const int lr = ln & 15, lg = ln >> 4;
  const int g0 = gt*16;
  const int kbeg = (ks == 0) ? 0 : 2176 + (ks - 1)*2112;
  const int nsteps = (ks == 0) ? 34 : 33;
  const unsigned short* An = mem + (size_t)n*128*AK;
  const float* Bn = Wih + (size_t)(n*G4H + g0)*MEMIN;

#define STAGE5(bb, kk) do{                                                     \
    _Pragma("unroll")                                                          \
    for(int i_ = 0; i_ < 4; ++i_){                                             \
      const int ci_ = i_*256 + tid;                                            \
      const int row_ = ci_ >> 3;                                               \
      const unsigned short* src_ = An + (size_t)row_*AK + (kk)                 \
                                   + (((ci_ & 7) ^ (row_ & 7)) << 3);          \
      gl_lds16(src_, &Abuf[bb][(i_*256 + wv*64)*8]);                           \
    }                                                                          \
    _Pragma("unroll")                                                          \
    for(int q_ = 0; q_ < 4; ++q_){                                             \
      const int idx_ = q_*256 + tid;                                           \
      const int g_ = idx_ >> 6;                                                \
      const int kd_ = idx_ & 63;                                               \
      const float* srcB_ = Bn + (size_t)g_*MEMIN + (kk)                        \
                           + ((((kd_ >> 3) ^ (g_ & 7)) << 3) + (kd_ & 7));     \
      gl_lds4(srcB_, &Bbuf[bb][q_*256 + wv*64]);                               \
    }                                                                          \
  }while(0)

  f32x4 acc0 = {0.f,0.f,0.f,0.f};
  f32x4 acc1 = {0.f,0.f,0.f,0.f};

  STAGE5(0, kbeg);
  if(nsteps > 1) STAGE5(1, kbeg + KSTEP);

  int b = 0;
  for(int t = 0; t < nsteps; ++t){
    if(t < nsteps - 1){
      asm volatile("s_waitcnt vmcnt(8)" ::: "memory");
    } else {
      asm volatile("s_waitcnt vmcnt(0)" ::: "memory");
    }
    __builtin_amdgcn_s_barrier();
    #pragma unroll
    for(int s = 0; s < 2; ++s){
      const int jb = (s*4 + lg) ^ (lr & 7);
      const float* bp = &Bbuf[b][lr*64 + jb*8];
      const f32x4 blo = *(const f32x4*)bp;
      const f32x4 bhi = *(const f32x4*)(bp + 4);
      short8v bf;
      unsigned* u = (unsigned*)&bf;
      u[0] = pkbf(blo.x, blo.y); u[1] = pkbf(blo.z, blo.w);
      u[2] = pkbf(bhi.x, bhi.y); u[3] = pkbf(bhi.z, bhi.w);
      const short8v a0 = *(const short8v*)&Abuf[b][(wv*32 + lr)*64 + jb*8];
      const short8v a1 = *(const short8v*)&Abuf[b][(wv*32 + 16 + lr)*64 + jb*8];
      acc0 = __builtin_amdgcn_mfma_f32_16x16x32_bf16(a0, bf, acc0, 0, 0, 0);
      acc1 = __builtin_amdgcn_mfma_f32_16x16x32_bf16(a1, bf, acc1, 0, 0, 0);
    }
    __builtin_amdgcn_s_barrier();
    if(t + 2 < nsteps) STAGE5(b, kbeg + (t+2)*KSTEP);
    b ^= 1;
  }
#undef STAGE5

  float* dst = xg4 + (size_t)ks*XGN;
  const int c0 = g0 + lr;
  const int r0 = wv*32 + lg*4, r1 = r0 + 16;
  #pragma unroll
  for(int j = 0; j < 4; ++j){
    dst[(size_t)((r0 + j)*8 + n)*G4H + c0] = acc0[j];
    dst[(size_t)((r1 + j)*8 + n)*G4H + c0] = acc1[j];
  }
}

// ---------------------------------------------------------------------------
extern "C" void kernel_launch(void* const* d_in, const int* in_sizes, int n_in,
                              void* d_out, int out_size, void* d_ws, size_t ws_size,
                              hipStream_t stream)
{
  (void)in_sizes; (void)n_in; (void)out_size;
  const float* img  = (const float*)d_in[0];
  const float* tar  = (const float*)d_in[1];
  const float* WvB  = (const float*)d_in[7];
  const float* WoW  = (const float*)d_in[8];
  const float* WoB  = (const float*)d_in[9];
  const float* tdw  = (const float*)d_in[10];
  const float* tdb  = (const float*)d_in[11];
  const float* cw   = (const float*)d_in[12];
  const float* cb   = (const float*)d_in[13];
  const float* Wih  = (const float*)d_in[14];
  const float* Whh  = (const float*)d_in[15];
  const float* bih  = (const float*)d_in[16];
  const float* bhh  = (const float*)d_in[17];

  float* wsf   = (float*)d_ws;
  float* gatew = wsf;                       // 32768 f
  float* shw   = wsf + 32768;               // 128 f
  float* xgw   = wsf + 32896;               // 4 x 524288 f reserved (gemm7 uses 1)
  unsigned short* memA = (unsigned short*)((char*)d_ws + 8520192);   // 17.4 MB
  const size_t WS_7 = 8520192 + (size_t)8*128*AK*2;    // 25,952,768 B (known OK)

  k_shared<<<128, 64, 0, stream>>>(WvB, WoW, WoB, shw);
  k_gate<<<dim3(8, 8), 256, 0, stream>>>(tar, tdw, tdb, gatew);
  k_conv2<<<dim3(128, 8), 256, 0, stream>>>(img, gatew, cw, cb, shw, tar, memA);

  if(ws_size >= WS_7){
    (void)hipFuncSetAttribute((const void*)k_gemm7,
                              hipFuncAttributeMaxDynamicSharedMemorySize, 81920);
    k_gemm7<<<256, 256, 81920, stream>>>(memA, Wih, xgw);
    k_lstm2<<<64, 512, 0, stream>>>(xgw, 1, Whh, bih, bhh, (float*)d_out);
  } else {
    k_gemm5<<<dim3(32, 8, 4), 256, 0, stream>>>(memA, Wih, xgw);
    k_lstm2<<<64, 512, 0, stream>>>(xgw, 4, Whh, bih, bhh, (float*)d_out);
  }
}

// Round 12
// 122.546 us; speedup vs baseline: 1.1991x; 1.0209x over previous
//
#include <hip/hip_runtime.h>

#define T_   16
#define B_   8
#define N_   8
#define H_   128
#define C_   32
#define HW_  256
#define TAR_ 145
#define G4H  512
#define MEMIN 8593
#define AK   8512   // padded K (multiple of 64)
#define XGN  524288
#define KSTEP 64

typedef __attribute__((ext_vector_type(8))) short short8v;
typedef __attribute__((ext_vector_type(4))) float f32x4;
typedef __attribute__((ext_vector_type(4), aligned(4))) float f32x4u;

__device__ __forceinline__ float bf2f(unsigned short u){
  return __uint_as_float(((unsigned int)u) << 16);
}
__device__ __forceinline__ unsigned short f2bf(float x){
  unsigned int b = __float_as_uint(x);
  return (unsigned short)((b + 0x7fffu + ((b >> 16) & 1u)) >> 16);
}
__device__ __forceinline__ unsigned pkbf(float lo, float hi){
  return __builtin_amdgcn_perm(__float_as_uint(hi) + 0x8000u,
                               __float_as_uint(lo) + 0x8000u, 0x07060302u);
}
__device__ __forceinline__ float bflo(unsigned w){ return __uint_as_float(w << 16); }
__device__ __forceinline__ float bfhi(unsigned w){ return __uint_as_float(w & 0xffff0000u); }
__device__ __forceinline__ float sigf(float x){ return 1.f/(1.f + expf(-x)); }

__device__ __forceinline__ void gl_lds16(const void* g, void* l){
  __builtin_amdgcn_global_load_lds(
      (const __attribute__((address_space(1))) unsigned int*)g,
      (__attribute__((address_space(3))) unsigned int*)l, 16, 0, 0);
}
__device__ __forceinline__ void gl_lds4(const void* g, void* l){
  __builtin_amdgcn_global_load_lds(
      (const __attribute__((address_space(1))) unsigned int*)g,
      (__attribute__((address_space(3))) unsigned int*)l, 4, 0, 0);
}

// ---------------------------------------------------------------------------
// shared[h] = Wo_b[h] + sum_d Wv_b[d] * Wo_w[h,d]   (attention collapses)
// ---------------------------------------------------------------------------
__global__ void k_shared(const float* __restrict__ WvB, const float* __restrict__ WoW,
                         const float* __restrict__ WoB, float* __restrict__ sh){
  const int h = blockIdx.x, lane = threadIdx.x;
  float acc = 0.f;
  for(int d = lane; d < 896; d += 64) acc += WvB[d] * WoW[h*896 + d];
  for(int s = 32; s; s >>= 1) acc += __shfl_down(acc, s);
  if(lane == 0) sh[h] = acc + WoB[h];
}

// ---------------------------------------------------------------------------
// gate[tb,n,c] = sigmoid(td_b[n,c] + sum_{x<145} tar[tb,x]*td_w[n,c,x])
// ---------------------------------------------------------------------------
__global__ __launch_bounds__(256) void k_gate(const float* __restrict__ tar,
                                              const float* __restrict__ tdw,
                                              const float* __restrict__ tdb,
                                              float* __restrict__ gate){
  __shared__ float twS[32*145];
  __shared__ float taS[16*145];
  const int tb0 = blockIdx.x * 16, n = blockIdx.y, tid = threadIdx.x;
  for(int i = tid; i < 32*145; i += 256){
    int c = i / 145, x = i - c*145;
    twS[i] = tdw[(n*32 + c)*273 + x];
  }
  for(int i = tid; i < 16*145; i += 256)
    taS[i] = tar[tb0*145 + i];
  __syncthreads();
  for(int o = tid; o < 512; o += 256){
    int r = o >> 5, c = o & 31;
    float a = tdb[n*32 + c];
    const float* tr = &taS[r*145];
    const float* tw = &twS[c*145];
    for(int x = 0; x < 145; ++x) a += tr[x]*tw[x];
    gate[((tb0 + r)*N_ + n)*C_ + c] = 1.f/(1.f + expf(-a));
  }
}

// ---------------------------------------------------------------------------
// conv v2: grid (tb=128, n=8), 256 threads = hw.  Tail covers [8192..8512).
// ---------------------------------------------------------------------------
__global__ __launch_bounds__(256) void k_conv2(
    const float* __restrict__ img, const float* __restrict__ gate,
    const float* __restrict__ cw, const float* __restrict__ cb,
    const float* __restrict__ sh, const float* __restrict__ tar,
    unsigned short* __restrict__ mem)
{
  __shared__ float imgS[8192];    // [c][hw]
  __shared__ float cwgT[1024];    // [c][d] = cw[d][c]*gate[n][c]
  const int tb = blockIdx.x, n = blockIdx.y;
  const int hw = threadIdx.x;
  for(int i = hw; i < 8192; i += 256)
    imgS[i] = img[(size_t)tb*8192 + i];
  for(int i = hw; i < 1024; i += 256){
    const int c = i >> 5, d = i & 31;
    cwgT[i] = cw[d*32 + c] * gate[(tb*8 + n)*32 + c];
  }
  __syncthreads();
  f32x4 acc[8];
  #pragma unroll
  for(int dq = 0; dq < 8; ++dq){
    const f32x4u cv = *(const f32x4u*)&cb[dq*4];
    acc[dq].x = cv.x; acc[dq].y = cv.y; acc[dq].z = cv.z; acc[dq].w = cv.w;
  }
  #pragma unroll 4
  for(int c = 0; c < 32; ++c){
    const float iv = imgS[c*256 + hw];
    #pragma unroll
    for(int dq = 0; dq < 8; ++dq){
      const f32x4 w = *(const f32x4*)&cwgT[c*32 + dq*4];
      acc[dq].x += iv*w.x; acc[dq].y += iv*w.y;
      acc[dq].z += iv*w.z; acc[dq].w += iv*w.w;
    }
  }
  unsigned short* mrow = mem + (size_t)(n*128 + tb)*AK;
  #pragma unroll
  for(int dq = 0; dq < 8; ++dq){
    mrow[(dq*4 + 0)*256 + hw] = f2bf(acc[dq].x);
    mrow[(dq*4 + 1)*256 + hw] = f2bf(acc[dq].y);
    mrow[(dq*4 + 2)*256 + hw] = f2bf(acc[dq].z);
    mrow[(dq*4 + 3)*256 + hw] = f2bf(acc[dq].w);
  }
  for(int i = hw; i < 320; i += 256){
    if(i < 128)      mrow[8192 + i]       = f2bf(sh[i]);
    else if(i < 273) mrow[8320 + i - 128] = f2bf(tar[tb*TAR_ + i - 128]);
    else             mrow[8465 + i - 273] = 0;   // zeros to 8512
  }
}

// ---------------------------------------------------------------------------
// MFMA GEMM v8: minimize global_load_lds WAVE-OP COUNT (the invariant wall).
// Grid 256 = (8 gt x 8 n x 4 ks), XCD-pinned n.  Block tile 128r x 64g; wave
// owns 16 g (lr) x 128 rows, acc = 8 x f32x4.  Per stage (K=64):
//   A: 4 ops/wave width-16 (as rounds 8-11, verified)
//   B: 5 ops/wave width-16 via per-row 16B-ALIGNED window (pad = ridx%4
//      floats, 18 chunks/row covers pad+256B; OOB-clamped)
// -> 9 ops/wave/stage vs 32/block before; A re-read 32x -> 8x.
// Ring-4 LDS (4 x (16KB A + 20KB B) = 147456B), counted vmcnt(18/9/0).
// C/D: col=lane&15, row=(lane>>4)*4+j.
// ---------------------------------------------------------------------------
__global__ __launch_bounds__(256) void k_gemm8(
    const unsigned short* __restrict__ mem, const float* __restrict__ Wih,
    float* __restrict__ xg4)
{
  extern __shared__ char smem8[];
  unsigned short (*Abuf)[8192] = (unsigned short(*)[8192])smem8;   // 4 x 16KB
  float (*Bbuf)[5120] = (float(*)[5120])(smem8 + 4*16384);         // 4 x 20KB
  const int bid = blockIdx.x;
  const int n = bid & 7, r2 = bid >> 3;
  const int gt = r2 & 7, ks = r2 >> 3;
  const int tid = threadIdx.x;
  const int wv = tid >> 6, ln = tid & 63;
  const int lr = ln & 15, lg = ln >> 4;
  const int g0 = gt*64;
  const int kbeg = (ks == 0) ? 0 : 2176 + (ks - 1)*2112;
  const int nsteps = (ks == 0) ? 34 : 33;
  const unsigned short* An = mem + (size_t)n*128*AK;
  const int rbase = n*512 + g0 + wv*16;   // wave's first B row index

#define STAGE8(sl, kk) do{                                                     \
    _Pragma("unroll")                                                          \
    for(int i_ = 0; i_ < 4; ++i_){                                             \
      const int ci_ = i_*256 + tid;                                            \
      const int row_ = ci_ >> 3;                                               \
      gl_lds16(An + (size_t)row_*AK + (kk) + (((ci_ & 7) ^ (row_ & 7)) << 3),  \
               (char*)&Abuf[sl][0] + (i_*256 + wv*64)*16);                     \
    }                                                                          \
    _Pragma("unroll")                                                          \
    for(int o_ = 0; o_ < 5; ++o_){                                             \
      const int p_ = o_*64 + ln;                                               \
      int gl_ = p_ / 18;                                                       \
      const int c_ = p_ - gl_*18;                                              \
      if(gl_ > 15) gl_ = 15;                                                   \
      const size_t ridx_ = (size_t)(rbase + gl_);                              \
      const char* src_ = (const char*)Wih + ridx_*((size_t)MEMIN*4)            \
                         + (size_t)(kk)*4 - ((ridx_ & 3)*4) + c_*16;           \
      gl_lds16(src_, (char*)&Bbuf[sl][0] + wv*5120 + o_*1024);                 \
    }                                                                          \
  }while(0)

  f32x4 acc[8];
  #pragma unroll
  for(int rt = 0; rt < 8; ++rt){ acc[rt].x=0.f; acc[rt].y=0.f; acc[rt].z=0.f; acc[rt].w=0.f; }

  STAGE8(0, kbeg);
  STAGE8(1, kbeg + KSTEP);
  STAGE8(2, kbeg + 2*KSTEP);

  for(int t = 0; t < nsteps; ++t){
    if(t < nsteps - 2){
      asm volatile("s_waitcnt vmcnt(18)" ::: "memory");  // stage t done; t+1,t+2 in flight
    } else if(t == nsteps - 2){
      asm volatile("s_waitcnt vmcnt(9)" ::: "memory");
    } else {
      asm volatile("s_waitcnt vmcnt(0)" ::: "memory");
    }
    __builtin_amdgcn_s_barrier();
    const int sl = t & 3;
    const char* Ab = (const char*)&Abuf[sl][0];
    #pragma unroll
    for(int s = 0; s < 2; ++s){
      const int u = s*4 + lg;                            // real k-chunk (8 floats)
      const int fb = wv*1280 + lr*72 + (lr & 3) + u*8;
      const f32x4u blo = *(const f32x4u*)&Bbuf[sl][fb];
      const f32x4u bhi = *(const f32x4u*)&Bbuf[sl][fb + 4];
      short8v bf;
      unsigned* up = (unsigned*)&bf;
      up[0] = pkbf(blo.x, blo.y); up[1] = pkbf(blo.z, blo.w);
      up[2] = pkbf(bhi.x, bhi.y); up[3] = pkbf(bhi.z, bhi.w);
      const int jbx = u ^ (lr & 7);                      // stored chunk position
      #pragma unroll
      for(int rt = 0; rt < 8; ++rt){
        const short8v a = *(const short8v*)(Ab + (((rt*16 + lr)*8 + jbx) << 4));
        acc[rt] = __builtin_amdgcn_mfma_f32_16x16x32_bf16(a, bf, acc[rt], 0, 0, 0);
      }
    }
    if(t + 3 < nsteps) STAGE8((t + 3) & 3, kbeg + (t + 3)*KSTEP);
    // slot (t+3)&3 == (t-1)&3: readers ran in step t-1; this step's barrier
    // guarantees every wave finished step t-1.
  }
#undef STAGE8

  float* dst = xg4 + (size_t)ks*XGN;
  const int col = g0 + wv*16 + lr;
  #pragma unroll
  for(int rt = 0; rt < 8; ++rt){
    #pragma unroll
    for(int j = 0; j < 4; ++j){
      dst[(size_t)((rt*16 + lg*4 + j)*8 + n)*G4H + col] = acc[rt][j];
    }
  }
}

// ---------------------------------------------------------------------------
// LSTM v2: 64 blocks = (b,n) pairs, 512 threads = gate-row g.  nsum = number
// of K-split partial buffers to sum.
// ---------------------------------------------------------------------------
__global__ __launch_bounds__(512) void k_lstm2(
    const float* __restrict__ xg4, int nsum, const float* __restrict__ Whh,
    const float* __restrict__ bih, const float* __restrict__ bhh,
    float* __restrict__ out)
{
  __shared__ float hS[128];
  __shared__ float preS[512];
  const int bn = blockIdx.x;
  const int n = bn & 7, b = bn >> 3;
  const int g = threadIdx.x;

  unsigned wr[64];
  const float* wrow = Whh + (size_t)(n*G4H + g)*H_;
  #pragma unroll
  for(int i = 0; i < 32; ++i){
    const f32x4 w = *(const f32x4*)(wrow + i*4);
    wr[2*i]   = pkbf(w.x, w.y);
    wr[2*i+1] = pkbf(w.z, w.w);
  }
  const float bias = bih[n*G4H + g] + bhh[n*G4H + g];
  if(g < 128) hS[g] = 0.f;
  float cc = 0.f;
  __syncthreads();

  for(int t = 0; t < 16; ++t){
    const size_t xb = (size_t)((t*8 + b)*8 + n)*G4H + g;
    float acc = bias;
    for(int u = 0; u < nsum; ++u) acc += xg4[xb + (size_t)u*XGN];
    #pragma unroll
    for(int q = 0; q < 32; ++q){
      const f32x4 hv = *(const f32x4*)&hS[q*4];
      const unsigned w0 = wr[2*q], w1 = wr[2*q+1];
      acc += hv.x*bflo(w0) + hv.y*bfhi(w0) + hv.z*bflo(w1) + hv.w*bfhi(w1);
    }
    preS[g] = acc;
    __syncthreads();
    if(g < 128){
      const float iv = sigf(preS[g]);
      const float fv = sigf(preS[128 + g]);
      const float gv = tanhf(preS[256 + g]);
      const float ov = sigf(preS[384 + g]);
      cc = fv*cc + iv*gv;
      const float hn = ov*tanhf(cc);
      hS[g] = hn;
      out[(t*8 + b)*1024 + n*128 + g] = hn;
      if(t == 15){
        out[131072 + (b*8 + n)*128 + g] = hn;   // hT
        out[139264 + (b*8 + n)*128 + g] = cc;   // cT
      }
    }
    __syncthreads();
  }
}

// ---------------------------------------------------------------------------
// Fallback GEMM (round-9 verified): only used if ws too small for gemm8 tier.
// ---------------------------------------------------------------------------
__global__ __launch_bounds__(256) void k_gemm5(
    const unsigned short* __restrict__ mem, const float* __restrict__ Wih,
    float* __restrict__ xg4)
{
  __shared__ unsigned short Abuf[2][128*64];
  __shared__ float          Bbuf[2][16*64];
  const int gt = blockIdx.x, n = blockIdx.y, ks = blockIdx.z;
  const int tid = threadIdx.x;
  const int wv = tid >> 6, ln = tid & 63;
  const int lr = ln & 15, lg = ln >> 4;
  const int g0 = gt*16;
  const int kbeg = (ks == 0) ? 0 : 2176 + (ks - 1)*2112;
  const int nsteps = (ks == 0) ? 34 : 33;
  const unsigned short* An = mem + (size_t)n*128*AK;
  const float* Bn = Wih + (size_t)(n*G4H + g0)*MEMIN;

#define STAGE5(bb, kk) do{                                                     \
    _Pragma("unroll")                                                          \
    for(int i_ = 0; i_ < 4; ++i_){                                             \
      const int ci_ = i_*256 + tid;                                            \
      const int row_ = ci_ >> 3;                                               \
      const unsigned short* src_ = An + (size_t)row_*AK + (kk)                 \
                                   + (((ci_ & 7) ^ (row_ & 7)) << 3);          \
      gl_lds16(src_, &Abuf[bb][(i_*256 + wv*64)*8]);                           \
    }                                                                          \
    _Pragma("unroll")                                                          \
    for(int q_ = 0; q_ < 4; ++q_){                                             \
      const int idx_ = q_*256 + tid;                                           \
      const int g_ = idx_ >> 6;                                                \
      const int kd_ = idx_ & 63;                                               \
      const float* srcB_ = Bn + (size_t)g_*MEMIN + (kk)                        \
                           + ((((kd_ >> 3) ^ (g_ & 7)) << 3) + (kd_ & 7));     \
      gl_lds4(srcB_, &Bbuf[bb][q_*256 + wv*64]);                               \
    }                                                                          \
  }while(0)

  f32x4 acc0 = {0.f,0.f,0.f,0.f};
  f32x4 acc1 = {0.f,0.f,0.f,0.f};

  STAGE5(0, kbeg);
  if(nsteps > 1) STAGE5(1, kbeg + KSTEP);

  int b = 0;
  for(int t = 0; t < nsteps; ++t){
    if(t < nsteps - 1){
      asm volatile("s_waitcnt vmcnt(8)" ::: "memory");
    } else {
      asm volatile("s_waitcnt vmcnt(0)" ::: "memory");
    }
    __builtin_amdgcn_s_barrier();
    #pragma unroll
    for(int s = 0; s < 2; ++s){
      const int jb = (s*4 + lg) ^ (lr & 7);
      const float* bp = &Bbuf[b][lr*64 + jb*8];
      const f32x4 blo = *(const f32x4*)bp;
      const f32x4 bhi = *(const f32x4*)(bp + 4);
      short8v bf;
      unsigned* u = (unsigned*)&bf;
      u[0] = pkbf(blo.x, blo.y); u[1] = pkbf(blo.z, blo.w);
      u[2] = pkbf(bhi.x, bhi.y); u[3] = pkbf(bhi.z, bhi.w);
      const short8v a0 = *(const short8v*)&Abuf[b][(wv*32 + lr)*64 + jb*8];
      const short8v a1 = *(const short8v*)&Abuf[b][(wv*32 + 16 + lr)*64 + jb*8];
      acc0 = __builtin_amdgcn_mfma_f32_16x16x32_bf16(a0, bf, acc0, 0, 0, 0);
      acc1 = __builtin_amdgcn_mfma_f32_16x16x32_bf16(a1, bf, acc1, 0, 0, 0);
    }
    __builtin_amdgcn_s_barrier();
    if(t + 2 < nsteps) STAGE5(b, kbeg + (t+2)*KSTEP);
    b ^= 1;
  }
#undef STAGE5

  float* dst = xg4 + (size_t)ks*XGN;
  const int c0 = g0 + lr;
  const int r0 = wv*32 + lg*4, r1 = r0 + 16;
  #pragma unroll
  for(int j = 0; j < 4; ++j){
    dst[(size_t)((r0 + j)*8 + n)*G4H + c0] = acc0[j];
    dst[(size_t)((r1 + j)*8 + n)*G4H + c0] = acc1[j];
  }
}

// ---------------------------------------------------------------------------
extern "C" void kernel_launch(void* const* d_in, const int* in_sizes, int n_in,
                              void* d_out, int out_size, void* d_ws, size_t ws_size,
                              hipStream_t stream)
{
  (void)in_sizes; (void)n_in; (void)out_size;
  const float* img  = (const float*)d_in[0];
  const float* tar  = (const float*)d_in[1];
  const float* WvB  = (const float*)d_in[7];
  const float* WoW  = (const float*)d_in[8];
  const float* WoB  = (const float*)d_in[9];
  const float* tdw  = (const float*)d_in[10];
  const float* tdb  = (const float*)d_in[11];
  const float* cw   = (const float*)d_in[12];
  const float* cb   = (const float*)d_in[13];
  const float* Wih  = (const float*)d_in[14];
  const float* Whh  = (const float*)d_in[15];
  const float* bih  = (const float*)d_in[16];
  const float* bhh  = (const float*)d_in[17];

  float* wsf   = (float*)d_ws;
  float* gatew = wsf;                       // 32768 f
  float* shw   = wsf + 32768;               // 128 f
  float* xgw   = wsf + 32896;               // 4 x 524288 f
  unsigned short* memA = (unsigned short*)((char*)d_ws + 8520192);   // 17.4 MB
  const size_t WS_7 = 8520192 + (size_t)8*128*AK*2;    // 25,952,768 B (known OK)

  k_shared<<<128, 64, 0, stream>>>(WvB, WoW, WoB, shw);
  k_gate<<<dim3(8, 8), 256, 0, stream>>>(tar, tdw, tdb, gatew);
  k_conv2<<<dim3(128, 8), 256, 0, stream>>>(img, gatew, cw, cb, shw, tar, memA);

  if(ws_size >= WS_7){
    (void)hipFuncSetAttribute((const void*)k_gemm8,
                              hipFuncAttributeMaxDynamicSharedMemorySize, 147456);
    k_gemm8<<<256, 256, 147456, stream>>>(memA, Wih, xgw);
    k_lstm2<<<64, 512, 0, stream>>>(xgw, 4, Whh, bih, bhh, (float*)d_out);
  } else {
    k_gemm5<<<dim3(32, 8, 4), 256, 0, stream>>>(memA, Wih, xgw);
    k_lstm2<<<64, 512, 0, stream>>>(xgw, 4, Whh, bih, bhh, (float*)d_out);
  }
}